// Round 10
// baseline (77.814 us; speedup 1.0000x reference)
//
#include <hip/hip_runtime.h>

#define S_LEN 8192
#define DIM   256
#define CHUNK 512
#define TB    64
#define NIT   8
#define NBLK  256

typedef __attribute__((ext_vector_type(8))) short          short8;
typedef __attribute__((ext_vector_type(4))) unsigned short u16x4;
typedef __attribute__((ext_vector_type(4))) unsigned int   u32x4;
typedef __attribute__((ext_vector_type(4))) float          f32x4;
typedef __attribute__((ext_vector_type(8))) __bf16         bf16x8;

static __device__ __forceinline__ unsigned short f2bf(float f){
  unsigned int u = __builtin_bit_cast(unsigned int, f);
  u = (u + 0x7fffu + ((u >> 16) & 1u)) >> 16;   // RNE
  return (unsigned short)u;
}
static __device__ __forceinline__ float bf2f(unsigned short h){
  unsigned int u = ((unsigned int)h) << 16;
  return __builtin_bit_cast(float, u);
}
static __device__ __forceinline__ float fast_tanh(float x){
  float e = __expf(2.0f * x);
  return 1.0f - 2.0f / (e + 1.0f);
}
static __device__ __forceinline__ f32x4 mfma_bf16(short8 a, short8 b, f32x4 c){
  return __builtin_amdgcn_mfma_f32_16x16x32_bf16(
      __builtin_bit_cast(bf16x8, a), __builtin_bit_cast(bf16x8, b), c, 0, 0, 0);
}
// barrier draining LDS ops only (no vmcnt drain)
static __device__ __forceinline__ void softbar(){
  asm volatile("s_waitcnt lgkmcnt(0)\n\ts_barrier" ::: "memory");
}

// ---- prep: KT[n][k] = bf16(k_kernel[k][n])
__global__ void k_prep(const float* __restrict__ kk, unsigned short* __restrict__ KT){
  int idx = blockIdx.x * 512 + threadIdx.x;     // 128 x 512 = 65536
  int n = idx >> 8, k = idx & 255;
  KT[(n << 8) + k] = f2bf(kk[(k << 8) + n]);
}

// sX  phase1 (sXB): (r,d) at dblk*2048 + srow*32 + off; dblk=d>>4, srow=r^(dblk&3),
//                   off=((d&15)*2)^(((srow>>2)&1)<<4)        (d-contig, GEMM1-B)
// sX  phase2 (sXT2): (r,d) at d*128 + ((r*2)^(key(d)<<4)), key=((d&3)<<1)^((d>>2)&7)
// sT2P phase1 (sT2): tanh [32? no: 64 rows][256 hid] bf16, swz ((row&7)<<4)
// sT2P phase2 (sP) : P^T [16 head][512 row] bf16, row-major, head stride 1040 B
// sSC : scores f32 [512 row][16 head], row stride 68 B

__global__ __launch_bounds__(512, 2) void k_main(
    const float* __restrict__ x, const int* __restrict__ mask,
    const float* __restrict__ ok, const unsigned short* __restrict__ KT,
    float* __restrict__ ACC, float* __restrict__ ML)
{
  __shared__ __align__(16) unsigned char sX  [32768];
  __shared__ __align__(16) unsigned char sT2P[32768];
  __shared__ __align__(16) unsigned char sSC [34816];
  __shared__ __align__(16) unsigned char sOT [16*528];
  __shared__ float sRed[32][16];
  __shared__ float sM[16];
  __shared__ float sL[16];
  __shared__ float sMaskB[CHUNK];

  const int tid = threadIdx.x;
  const int w   = tid >> 6;      // wave 0..7
  const int l   = tid & 63;
  const int l15 = l & 15;
  const int lhi = l >> 4;        // 0..3
  const int bid = blockIdx.x;
  const int b   = bid >> 4;
  const int chunk0 = (bid & 15) * CHUNK;

  // O^T init (heads 8..15 zero-padded)
  for (int idx = tid; idx < 16 * 256; idx += 512){
    int h = idx >> 8, k = idx & 255;
    float v = (h < 8) ? ok[k * 8 + h] : 0.0f;
    *(unsigned short*)(sOT + h * 528 + k * 2) = f2bf(v);
  }
  sMaskB[tid] = mask[(size_t)b * S_LEN + chunk0 + tid] ? 0.0f : 1e12f;

  // persistent K^T fragments: wave (h4 = w&3) owns hidden cols [64*h4, 64*h4+64)
  const int h4 = w & 3;
  const int rh = w >> 2;         // row-half for P1
  short8 aF[4][8];
  #pragma unroll
  for (int mi = 0; mi < 4; ++mi){
    int hidA = l15 + ((4*h4 + mi) << 4);
    #pragma unroll
    for (int k = 0; k < 8; ++k){
      int col = (k << 5) + (lhi << 3);
      aF[mi][k] = *(const short8*)((const unsigned char*)KT + (((size_t)hidA << 8) + col) * 2);
    }
  }

  const unsigned char* xb = (const unsigned char*)(x + ((size_t)b * S_LEN + chunk0) * DIM);

  // first tile into regs: wave w owns rows 8w..8w+7; lane l owns d = 4l..4l+3
  f32x4 xr[8];
  #pragma unroll
  for (int q = 0; q < 8; ++q)
    xr[q] = *(const f32x4*)(xb + (((size_t)(8*w + q)) * DIM + 4*l) * 4);

  __syncthreads();

  // ================= PHASE 1: scores for all 512 rows =================
  for (int it = 0; it < NIT; ++it){
    // ---- P0: stage tile to sX (sXB layout), prefetch next
    unsigned vd[8][2];
    #pragma unroll
    for (int q = 0; q < 8; ++q){
      vd[q][0] = (unsigned)f2bf(xr[q][0]) | ((unsigned)f2bf(xr[q][1]) << 16);
      vd[q][1] = (unsigned)f2bf(xr[q][2]) | ((unsigned)f2bf(xr[q][3]) << 16);
    }
    {
      int dblk = l >> 2;
      #pragma unroll
      for (int q = 0; q < 8; ++q){
        int r = 8*w + q;
        int srow = r ^ (dblk & 3);
        int off = ((l & 3) * 8) ^ (((srow >> 2) & 1) << 4);
        *(uint2*)(sX + dblk * 2048 + srow * 32 + off) = make_uint2(vd[q][0], vd[q][1]);
      }
    }
    if (it + 1 < NIT){
      #pragma unroll
      for (int q = 0; q < 8; ++q)
        xr[q] = *(const f32x4*)(xb + (((size_t)((it+1)*TB + 8*w + q)) * DIM + 4*l) * 4);
    }
    softbar();

    // ---- P1: GEMM1^T, wave (h4, rh): hid 64-slice, row-half; tanh -> sT2
    #pragma unroll
    for (int nt2 = 0; nt2 < 2; ++nt2){
      int row = l15 + ((2*rh + nt2) << 4);
      f32x4 a0 = (f32x4){0.f,0.f,0.f,0.f};
      f32x4 a1 = a0, a2v = a0, a3 = a0;
      #pragma unroll
      for (int k8 = 0; k8 < 8; ++k8){
        int dblkR = k8 * 2 + (lhi >> 1);
        int srowB = row ^ (dblkR & 3);
        int off = ((lhi & 1) * 16) ^ (((srowB >> 2) & 1) << 4);
        short8 bF = *(const short8*)(sX + dblkR * 2048 + srowB * 32 + off);
        a0  = mfma_bf16(aF[0][k8], bF, a0);
        a1  = mfma_bf16(aF[1][k8], bF, a1);
        a2v = mfma_bf16(aF[2][k8], bF, a2v);
        a3  = mfma_bf16(aF[3][k8], bF, a3);
      }
      f32x4 av[4] = {a0, a1, a2v, a3};
      #pragma unroll
      for (int mi = 0; mi < 4; ++mi){
        u16x4 tv;
        #pragma unroll
        for (int r = 0; r < 4; ++r) tv[r] = f2bf(fast_tanh(av[mi][r]));
        int hidb2 = ((((4*h4 + mi) << 4) + (lhi << 2))) * 2;
        *(u16x4*)(sT2P + row * 512 + (hidb2 ^ ((row & 7) << 4))) = tv;
      }
    }
    softbar();

    // ---- P2: GEMM2 -> biased scores into sSC   (waves 0..3)
    if (w < 4){
      int row = l15 + (w << 4);
      f32x4 a2 = (f32x4){0.f,0.f,0.f,0.f};
      #pragma unroll
      for (int k = 0; k < 8; ++k){
        int col2 = (k << 6) + (lhi << 4);
        short8 aT = *(const short8*)(sT2P + row * 512 + (col2 ^ ((row & 7) << 4)));
        short8 bO = *(const short8*)(sOT + l15 * 528 + col2);
        a2 = mfma_bf16(aT, bO, a2);
      }
      int rbase = (w << 4) + (lhi << 2);
      #pragma unroll
      for (int r = 0; r < 4; ++r){
        float sc = a2[r] - sMaskB[it * TB + rbase + r];
        *(float*)(sSC + (it * TB + rbase + r) * 68 + l15 * 4) = sc;
      }
    }
    softbar();
  }

  // ================= BOUNDARY: chunk softmax =================
  // issue phase-2 tile-0 loads early (L2-hot; no vmcnt drain until use)
  #pragma unroll
  for (int q = 0; q < 8; ++q)
    xr[q] = *(const f32x4*)(xb + (((size_t)(8*w + q)) * DIM + 4*l) * 4);

  {
    int seg = tid >> 4, head = tid & 15;
    float m = -1e30f;
    #pragma unroll
    for (int j = 0; j < 16; ++j)
      m = fmaxf(m, *(const float*)(sSC + (seg * 16 + j) * 68 + head * 4));
    sRed[seg][head] = m;
  }
  softbar();
  if (tid < 16){
    float m = -1e30f;
    #pragma unroll
    for (int s = 0; s < 32; ++s) m = fmaxf(m, sRed[s][tid]);
    sM[tid] = m;
  }
  softbar();
  {
    int head = tid >> 5, rseg = tid & 31;
    float M = sM[head];
    float psum = 0.0f;
    unsigned pk[8];
    #pragma unroll
    for (int jj = 0; jj < 8; ++jj){
      float s0 = *(const float*)(sSC + (rseg * 16 + 2*jj    ) * 68 + head * 4);
      float s1 = *(const float*)(sSC + (rseg * 16 + 2*jj + 1) * 68 + head * 4);
      unsigned short p0 = f2bf(__expf(s0 - M));
      unsigned short p1 = f2bf(__expf(s1 - M));
      psum += bf2f(p0) + bf2f(p1);
      pk[jj] = (unsigned)p0 | ((unsigned)p1 << 16);
    }
    *(u32x4*)(sT2P + head * 1040 + rseg * 32     ) = (u32x4){pk[0],pk[1],pk[2],pk[3]};
    *(u32x4*)(sT2P + head * 1040 + rseg * 32 + 16) = (u32x4){pk[4],pk[5],pk[6],pk[7]};
    sRed[rseg][head] = psum;
  }
  softbar();
  if (tid < 16){
    float s = 0.0f;
    #pragma unroll
    for (int r = 0; r < 32; ++r) s += sRed[r][tid];
    sL[tid] = s;
  }

  // ================= PHASE 2: pooling =================
  f32x4 acc3[2];
  acc3[0] = (f32x4){0.f,0.f,0.f,0.f};
  acc3[1] = acc3[0];

  for (int it = 0; it < NIT; ++it){
    // stage tile (d-major sXT2 layout) from regs; prefetch next (L2-hot)
    unsigned vd[8][2];
    #pragma unroll
    for (int q = 0; q < 8; ++q){
      vd[q][0] = (unsigned)f2bf(xr[q][0]) | ((unsigned)f2bf(xr[q][1]) << 16);
      vd[q][1] = (unsigned)f2bf(xr[q][2]) | ((unsigned)f2bf(xr[q][3]) << 16);
    }
    #pragma unroll
    for (int i = 0; i < 4; ++i){
      int hh = i >> 1;
      unsigned dwv[4];
      #pragma unroll
      for (int j = 0; j < 4; ++j){
        unsigned a = vd[2*j][hh], c = vd[2*j+1][hh];
        dwv[j] = (i & 1) ? ((a >> 16) | (c & 0xFFFF0000u))
                         : ((a & 0xFFFFu) | (c << 16));
      }
      int d = 4*l + i;
      int key = ((d & 3) << 1) ^ ((d >> 2) & 7);
      *(u32x4*)(sX + d * 128 + ((16*w) ^ (key << 4))) =
          (u32x4){dwv[0], dwv[1], dwv[2], dwv[3]};
    }
    if (it + 1 < NIT){
      #pragma unroll
      for (int q = 0; q < 8; ++q)
        xr[q] = *(const f32x4*)(xb + (((size_t)((it+1)*TB + 8*w + q)) * DIM + 4*l) * 4);
    }
    softbar();

    // GEMM3: pooled[head][d] += P^T · X
    {
      short8 aP0 = *(const short8*)(sT2P + l15 * 1040 + it * 128 +      lhi * 16);
      short8 aP1 = *(const short8*)(sT2P + l15 * 1040 + it * 128 + 64 + lhi * 16);
      #pragma unroll
      for (int mi = 0; mi < 2; ++mi){
        int d = (2*w + mi) * 16 + l15;
        int key = ((d & 3) << 1) ^ ((d >> 2) & 7);
        const unsigned char* pd = sX + d * 128;
        short8 b0 = *(const short8*)(pd + (((     lhi * 16)) ^ (key << 4)));
        short8 b1 = *(const short8*)(pd + (((64 + lhi * 16)) ^ (key << 4)));
        acc3[mi] = mfma_bf16(aP0, b0, acc3[mi]);
        acc3[mi] = mfma_bf16(aP1, b1, acc3[mi]);
      }
    }
    softbar();
  }

  // epilogue: per-chunk partials.  acc3[mi]: head = lhi*4+reg, d = (2w+mi)*16 + l15
  if (lhi < 2){      // only heads 0..7 are real
    #pragma unroll
    for (int mi = 0; mi < 2; ++mi){
      int d = ((2*w + mi) << 4) + l15;
      #pragma unroll
      for (int r = 0; r < 4; ++r){
        int h = (lhi << 2) + r;
        ACC[((size_t)bid * 8 + h) * 256 + d] = acc3[mi][r];
      }
    }
  }
  if (tid < 8){
    ML[bid * 16 + tid]     = sM[tid];
    ML[bid * 16 + 8 + tid] = sL[tid];
  }
}

// ---- merge 16 chunk-partials per (batch, head)
__global__ void k_merge(const float* __restrict__ ACC, const float* __restrict__ ML,
                        float* __restrict__ out){
  int b = blockIdx.x >> 3;
  int h = blockIdx.x & 7;
  int d = threadIdx.x;                      // 256
  float M = -1e30f;
  #pragma unroll
  for (int c = 0; c < 16; ++c) M = fmaxf(M, ML[(b * 16 + c) * 16 + h]);
  float L = 0.0f, V = 0.0f;
  #pragma unroll 4
  for (int c = 0; c < 16; ++c){
    int blk = b * 16 + c;
    float e = __expf(ML[blk * 16 + h] - M);
    L += e * ML[blk * 16 + 8 + h];
    V += e * ACC[((size_t)blk * 8 + h) * 256 + d];
  }
  out[(size_t)b * 2048 + h * 256 + d] = V / L;
}

extern "C" void kernel_launch(void* const* d_in, const int* in_sizes, int n_in,
                              void* d_out, int out_size, void* d_ws, size_t ws_size,
                              hipStream_t stream){
  const float* x   = (const float*)d_in[0];
  const int*  mask = (const int*) d_in[1];
  const float* kk  = (const float*)d_in[2];
  const float* ok  = (const float*)d_in[3];
  float* out = (float*)d_out;

  // ws layout: KT bf16 (128 KiB) | ACC f32 256*8*256 (2 MiB) | ML f32 256*16 (16 KiB)
  unsigned short* KT = (unsigned short*)d_ws;
  float* ACC = (float*)((char*)d_ws + 131072);
  float* ML  = (float*)((char*)d_ws + 131072 + 2097152);

  k_prep <<<128, 512, 0, stream>>>(kk, KT);
  k_main <<<NBLK, 512, 0, stream>>>(x, mask, ok, KT, ACC, ML);
  k_merge<<<128, 256, 0, stream>>>(ACC, ML, out);
}

// Round 11
// 62.432 us; speedup vs baseline: 1.2464x; 1.2464x over previous
//
#include <hip/hip_runtime.h>

#define S_LEN 8192
#define DIM   256
#define CHUNK 512
#define TB    64
#define NIT   8
#define NBLK  256

typedef __attribute__((ext_vector_type(8))) short          short8;
typedef __attribute__((ext_vector_type(4))) unsigned short u16x4;
typedef __attribute__((ext_vector_type(4))) unsigned int   u32x4;
typedef __attribute__((ext_vector_type(4))) float          f32x4;
typedef __attribute__((ext_vector_type(8))) __bf16         bf16x8;

static __device__ __forceinline__ unsigned short f2bf(float f){
  unsigned int u = __builtin_bit_cast(unsigned int, f);
  u = (u + 0x7fffu + ((u >> 16) & 1u)) >> 16;   // RNE
  return (unsigned short)u;
}
static __device__ __forceinline__ float bf2f(unsigned short h){
  unsigned int u = ((unsigned int)h) << 16;
  return __builtin_bit_cast(float, u);
}
static __device__ __forceinline__ float fast_tanh(float x){
  float e = __expf(2.0f * x);
  return 1.0f - 2.0f / (e + 1.0f);
}
static __device__ __forceinline__ f32x4 mfma_bf16(short8 a, short8 b, f32x4 c){
  return __builtin_amdgcn_mfma_f32_16x16x32_bf16(
      __builtin_bit_cast(bf16x8, a), __builtin_bit_cast(bf16x8, b), c, 0, 0, 0);
}
// barrier draining LDS ops only (no vmcnt drain)
static __device__ __forceinline__ void softbar(){
  asm volatile("s_waitcnt lgkmcnt(0)\n\ts_barrier" ::: "memory");
}

// ---- prep: KT[n][k] = bf16(k_kernel[k][n])
__global__ void k_prep(const float* __restrict__ kk, unsigned short* __restrict__ KT){
  int idx = blockIdx.x * 512 + threadIdx.x;     // 128 x 512 = 65536
  int n = idx >> 8, k = idx & 255;
  KT[(n << 8) + k] = f2bf(kk[(k << 8) + n]);
}

// sXB : (r,d) at dblk*2048 + srow*32 + off; dblk=d>>4, srow=r^(dblk&3),
//       off=((d&15)*2)^(((srow>>2)&1)<<4)        (d-contig, GEMM1-B)  [R5-verified]
// sXT2: (r,d) at buf*32768 + d*128 + ((r*2)^(key(d)<<4)), key=((d&3)<<1)^((d>>2)&7)
//       (r-contig, GEMM3-B)  [R5-verified, now double-buffered]

__global__ __launch_bounds__(512, 2) void k_main(
    const float* __restrict__ x, const int* __restrict__ mask,
    const float* __restrict__ ok, const unsigned short* __restrict__ KT,
    float* __restrict__ ACC, float* __restrict__ ML)
{
  __shared__ __align__(16) unsigned char sXB [32768];
  __shared__ __align__(16) unsigned char sXT2[65536];   // 2 buffers
  __shared__ __align__(16) unsigned char sT2 [32768];   // tanh(h) [64][256] bf16, swz ((row&7)<<4)
  __shared__ __align__(16) unsigned char sOT [16*528];  // O^T [16][256] bf16 (+pad), rows 8..15 zero
  __shared__ __align__(16) unsigned char sPT [16*144];  // P^T [16][64] bf16 (+pad)
  __shared__ float sWSum[4][16];
  __shared__ float sMaskB[CHUNK];

  const int tid = threadIdx.x;
  const int w   = tid >> 6;      // wave 0..7
  const int l   = tid & 63;
  const int l15 = l & 15;
  const int lhi = l >> 4;        // 0..3
  const int bid = blockIdx.x;
  const int b   = bid >> 4;
  const int chunk0 = (bid & 15) * CHUNK;

  // O^T init (heads 8..15 zero-padded)
  for (int idx = tid; idx < 16 * 256; idx += 512){
    int h = idx >> 8, k = idx & 255;
    float v = (h < 8) ? ok[k * 8 + h] : 0.0f;
    *(unsigned short*)(sOT + h * 528 + k * 2) = f2bf(v);
  }
  sMaskB[tid] = mask[(size_t)b * S_LEN + chunk0 + tid] ? 0.0f : 1e12f;

  // persistent K^T fragments: wave w owns hidden cols [32w, 32w+32)
  short8 aF[2][8];
  #pragma unroll
  for (int mi = 0; mi < 2; ++mi){
    int hidA = l15 + ((2*w + mi) << 4);
    #pragma unroll
    for (int k = 0; k < 8; ++k){
      int col = (k << 5) + (lhi << 3);
      aF[mi][k] = *(const short8*)((const unsigned char*)KT + (((size_t)hidA << 8) + col) * 2);
    }
  }

  const unsigned char* xb = (const unsigned char*)(x + ((size_t)b * S_LEN + chunk0) * DIM);
  const int dblk = l >> 2;

  // ---- prologue: tile 0 -> regs -> stage sXB + sXT2[0]; then load tile 1
  f32x4 xr[8];
  #pragma unroll
  for (int q = 0; q < 8; ++q)
    xr[q] = *(const f32x4*)(xb + (((size_t)(8*w + q)) * DIM + 4*l) * 4);

  unsigned vd[8][2];
  #pragma unroll
  for (int q = 0; q < 8; ++q){
    vd[q][0] = (unsigned)f2bf(xr[q][0]) | ((unsigned)f2bf(xr[q][1]) << 16);
    vd[q][1] = (unsigned)f2bf(xr[q][2]) | ((unsigned)f2bf(xr[q][3]) << 16);
  }
  #pragma unroll
  for (int q = 0; q < 8; ++q){
    int r = 8*w + q;
    int srow = r ^ (dblk & 3);
    int off = ((l & 3) * 8) ^ (((srow >> 2) & 1) << 4);
    *(uint2*)(sXB + dblk * 2048 + srow * 32 + off) = make_uint2(vd[q][0], vd[q][1]);
  }
  #pragma unroll
  for (int i = 0; i < 4; ++i){
    int hh = i >> 1;
    unsigned dwv[4];
    #pragma unroll
    for (int j = 0; j < 4; ++j){
      unsigned a = vd[2*j][hh], c = vd[2*j+1][hh];
      dwv[j] = (i & 1) ? ((a >> 16) | (c & 0xFFFF0000u)) : ((a & 0xFFFFu) | (c << 16));
    }
    int d = 4*l + i;
    int key = ((d & 3) << 1) ^ ((d >> 2) & 7);
    *(u32x4*)(sXT2 + d * 128 + ((16*w) ^ (key << 4))) = (u32x4){dwv[0],dwv[1],dwv[2],dwv[3]};
  }
  #pragma unroll
  for (int q = 0; q < 8; ++q)
    xr[q] = *(const f32x4*)(xb + (((size_t)(TB + 8*w + q)) * DIM + 4*l) * 4);

  f32x4 acc3[2];
  acc3[0] = (f32x4){0.f,0.f,0.f,0.f};
  acc3[1] = acc3[0];
  float Lrun = 0.0f;

  __syncthreads();

  for (int it = 0; it < NIT; ++it){
    const int cur = it & 1;

    // ======== Phase A: stage sXT2[next] (tile it+1) + GEMM1 + tanh -> sT2 ========
    if (it + 1 < NIT){
      #pragma unroll
      for (int q = 0; q < 8; ++q){
        vd[q][0] = (unsigned)f2bf(xr[q][0]) | ((unsigned)f2bf(xr[q][1]) << 16);
        vd[q][1] = (unsigned)f2bf(xr[q][2]) | ((unsigned)f2bf(xr[q][3]) << 16);
      }
      unsigned char* dst = sXT2 + (cur ^ 1) * 32768;
      #pragma unroll
      for (int i = 0; i < 4; ++i){
        int hh = i >> 1;
        unsigned dwv[4];
        #pragma unroll
        for (int j = 0; j < 4; ++j){
          unsigned a = vd[2*j][hh], c = vd[2*j+1][hh];
          dwv[j] = (i & 1) ? ((a >> 16) | (c & 0xFFFF0000u)) : ((a & 0xFFFFu) | (c << 16));
        }
        int d = 4*l + i;
        int key = ((d & 3) << 1) ^ ((d >> 2) & 7);
        *(u32x4*)(dst + d * 128 + ((16*w) ^ (key << 4))) = (u32x4){dwv[0],dwv[1],dwv[2],dwv[3]};
      }
    }
    #pragma unroll
    for (int nt = 0; nt < 4; ++nt){
      int row = l15 + (nt << 4);
      f32x4 a0 = (f32x4){0.f,0.f,0.f,0.f};
      f32x4 a1 = a0;
      #pragma unroll
      for (int k8 = 0; k8 < 8; ++k8){
        int dblkR = k8 * 2 + (lhi >> 1);
        int srowB = row ^ (dblkR & 3);
        int off = ((lhi & 1) * 16) ^ (((srowB >> 2) & 1) << 4);
        short8 bF = *(const short8*)(sXB + dblkR * 2048 + srowB * 32 + off);
        a0 = mfma_bf16(aF[0][k8], bF, a0);
        a1 = mfma_bf16(aF[1][k8], bF, a1);
      }
      #pragma unroll
      for (int mi = 0; mi < 2; ++mi){
        f32x4 av = mi ? a1 : a0;
        u16x4 tv;
        #pragma unroll
        for (int r = 0; r < 4; ++r) tv[r] = f2bf(fast_tanh(av[r]));
        int hidb2 = ((((2*w + mi) << 4) + (lhi << 2))) * 2;
        *(u16x4*)(sT2 + row * 512 + (hidb2 ^ ((row & 7) << 4))) = tv;
      }
    }
    softbar();

    // ======== Phase B: stage sXB (tile it+1) + GEMM2+exp (waves 0-3) + prefetch t+2 ========
    if (it + 1 < NIT){
      #pragma unroll
      for (int q = 0; q < 8; ++q){
        int r = 8*w + q;
        int srow = r ^ (dblk & 3);
        int off = ((l & 3) * 8) ^ (((srow >> 2) & 1) << 4);
        *(uint2*)(sXB + dblk * 2048 + srow * 32 + off) = make_uint2(vd[q][0], vd[q][1]);
      }
    }
    if (w < 4){
      int row = l15 + (w << 4);
      f32x4 a2 = (f32x4){0.f,0.f,0.f,0.f};
      #pragma unroll
      for (int k = 0; k < 8; ++k){
        int col2 = (k << 6) + (lhi << 4);
        short8 aT = *(const short8*)(sT2 + row * 512 + (col2 ^ ((row & 7) << 4)));
        short8 bO = *(const short8*)(sOT + l15 * 528 + col2);
        a2 = mfma_bf16(aT, bO, a2);
      }
      int rbase = (w << 4) + (lhi << 2);
      float psum = 0.0f;
      #pragma unroll
      for (int r = 0; r < 4; ++r){
        // no-max softmax: |sc| <= ||O_col||_1 ~ 13 << 88, exp cannot overflow;
        // masked rows: exp(sc - 1e12) == 0
        float p = __expf(a2[r] - sMaskB[it * TB + rbase + r]);
        unsigned short pb = f2bf(p);
        psum += bf2f(pb);
        *(unsigned short*)(sPT + l15 * 144 + (rbase + r) * 2) = pb;
      }
      psum += __shfl_xor(psum, 16);
      psum += __shfl_xor(psum, 32);
      Lrun += psum;                 // every lane: head l15 total over this wave's 16 rows
    }
    if (it + 2 < NIT){
      #pragma unroll
      for (int q = 0; q < 8; ++q)
        xr[q] = *(const f32x4*)(xb + (((size_t)((it+2)*TB + 8*w + q)) * DIM + 4*l) * 4);
    }
    softbar();

    // ======== Phase C: GEMM3: pooled[head][d] += P^T · X  (reads sXT2[cur], sPT) ========
    {
      short8 aP0 = *(const short8*)(sPT + l15 * 144 + lhi * 16);        // r 0..31
      short8 aP1 = *(const short8*)(sPT + l15 * 144 + 64 + lhi * 16);   // r 32..63
      const unsigned char* srcX = sXT2 + cur * 32768;
      #pragma unroll
      for (int mi = 0; mi < 2; ++mi){
        int d = (2*w + mi) * 16 + l15;
        int key = ((d & 3) << 1) ^ ((d >> 2) & 7);
        const unsigned char* pd = srcX + d * 128;
        short8 b0 = *(const short8*)(pd + (((     lhi * 16)) ^ (key << 4)));
        short8 b1 = *(const short8*)(pd + (((64 + lhi * 16)) ^ (key << 4)));
        acc3[mi] = mfma_bf16(aP0, b0, acc3[mi]);
        acc3[mi] = mfma_bf16(aP1, b1, acc3[mi]);
      }
    }
    softbar();
  }

  // epilogue: per-chunk partials.  acc3[mi]: head = lhi*4+reg, d = (2w+mi)*16 + l15
  if (lhi < 2){      // only heads 0..7 are real
    #pragma unroll
    for (int mi = 0; mi < 2; ++mi){
      int d = ((2*w + mi) << 4) + l15;
      #pragma unroll
      for (int r = 0; r < 4; ++r){
        int h = (lhi << 2) + r;
        ACC[((size_t)bid * 8 + h) * 256 + d] = acc3[mi][r];
      }
    }
  }
  if (w < 4 && l < 16) sWSum[w][l] = Lrun;
  __syncthreads();
  if (tid < 8)
    ML[bid * 8 + tid] = sWSum[0][tid] + sWSum[1][tid] + sWSum[2][tid] + sWSum[3][tid];
}

// ---- merge 16 chunk-partials per (batch, head): no max needed (fixed shift = 0)
__global__ void k_merge(const float* __restrict__ ACC, const float* __restrict__ ML,
                        float* __restrict__ out){
  int b = blockIdx.x >> 3;
  int h = blockIdx.x & 7;
  int d = threadIdx.x;                      // 256
  float L = 0.0f, V = 0.0f;
  #pragma unroll 4
  for (int c = 0; c < 16; ++c){
    int blk = b * 16 + c;
    L += ML[blk * 8 + h];
    V += ACC[((size_t)blk * 8 + h) * 256 + d];
  }
  out[(size_t)b * 2048 + h * 256 + d] = V / L;
}

extern "C" void kernel_launch(void* const* d_in, const int* in_sizes, int n_in,
                              void* d_out, int out_size, void* d_ws, size_t ws_size,
                              hipStream_t stream){
  const float* x   = (const float*)d_in[0];
  const int*  mask = (const int*) d_in[1];
  const float* kk  = (const float*)d_in[2];
  const float* ok  = (const float*)d_in[3];
  float* out = (float*)d_out;

  // ws layout: KT bf16 (128 KiB) | ACC f32 256*8*256 (2 MiB) | ML f32 256*8 (8 KiB)
  unsigned short* KT = (unsigned short*)d_ws;
  float* ACC = (float*)((char*)d_ws + 131072);
  float* ML  = (float*)((char*)d_ws + 131072 + 2097152);

  k_prep <<<128, 512, 0, stream>>>(kk, KT);
  k_main <<<NBLK, 512, 0, stream>>>(x, mask, ok, KT, ACC, ML);
  k_merge<<<128, 256, 0, stream>>>(ACC, ML, out);
}

// Round 12
// 58.228 us; speedup vs baseline: 1.3364x; 1.0722x over previous
//
#include <hip/hip_runtime.h>

#define S_LEN 8192
#define DIM   256
#define CHUNK 512
#define TB    64
#define NIT   8
#define NBLK  256

typedef __attribute__((ext_vector_type(8))) short          short8;
typedef __attribute__((ext_vector_type(4))) unsigned short u16x4;
typedef __attribute__((ext_vector_type(4))) unsigned int   u32x4;
typedef __attribute__((ext_vector_type(4))) float          f32x4;
typedef __attribute__((ext_vector_type(8))) __bf16         bf16x8;

// native cast -> v_cvt_pk_bf16_f32 (RNE, same bits as hand-RNE, 1/4 the VALU)
static __device__ __forceinline__ unsigned short f2bf(float f){
  return __builtin_bit_cast(unsigned short, (__bf16)f);
}
static __device__ __forceinline__ unsigned pk2bf(float lo, float hi){
  return (unsigned)f2bf(lo) | ((unsigned)f2bf(hi) << 16);
}
static __device__ __forceinline__ float bf2f(unsigned short h){
  unsigned int u = ((unsigned int)h) << 16;
  return __builtin_bit_cast(float, u);
}
static __device__ __forceinline__ float fast_tanh(float x){
  float e = __expf(2.0f * x);
  return 1.0f - 2.0f / (e + 1.0f);
}
static __device__ __forceinline__ f32x4 mfma_bf16(short8 a, short8 b, f32x4 c){
  return __builtin_amdgcn_mfma_f32_16x16x32_bf16(
      __builtin_bit_cast(bf16x8, a), __builtin_bit_cast(bf16x8, b), c, 0, 0, 0);
}
// barrier draining LDS ops only (no vmcnt drain)
static __device__ __forceinline__ void softbar(){
  asm volatile("s_waitcnt lgkmcnt(0)\n\ts_barrier" ::: "memory");
}

// ---- prep: KT[n][k] = bf16(k_kernel[k][n])
__global__ void k_prep(const float* __restrict__ kk, unsigned short* __restrict__ KT){
  int idx = blockIdx.x * 512 + threadIdx.x;     // 128 x 512 = 65536
  int n = idx >> 8, k = idx & 255;
  KT[(n << 8) + k] = f2bf(kk[(k << 8) + n]);
}

// sXB : (r,d) at dblk*2048 + srow*32 + off; dblk=d>>4, srow=r^(dblk&3),
//       off=((d&15)*2)^(((srow>>2)&1)<<4)        (d-contig, GEMM1-B)  [R5-verified]
// sXT2: (r,d) at buf*32768 + d*128 + ((r*2)^(key(d)<<4)), key=((d&3)<<1)^((d>>2)&7)
//       (r-contig, GEMM3-B)  [R5-verified, double-buffered]

__global__ __launch_bounds__(512, 2) void k_main(
    const float* __restrict__ x, const int* __restrict__ mask,
    const float* __restrict__ ok, const unsigned short* __restrict__ KT,
    float* __restrict__ ACC, float* __restrict__ ML)
{
  __shared__ __align__(16) unsigned char sXB [32768];
  __shared__ __align__(16) unsigned char sXT2[65536];   // 2 buffers
  __shared__ __align__(16) unsigned char sT2 [32768];   // tanh(h) [64][256] bf16, swz ((row&7)<<4)
  __shared__ __align__(16) unsigned char sOT [16*528];  // O^T [16][256] bf16 (+pad), rows 8..15 zero
  __shared__ __align__(16) unsigned char sPT [16*144];  // P^T [16][64] bf16 (+pad)
  __shared__ float sWSum[4][16];
  __shared__ float sMaskB[CHUNK];

  const int tid = threadIdx.x;
  const int w   = tid >> 6;      // wave 0..7
  const int l   = tid & 63;
  const int l15 = l & 15;
  const int lhi = l >> 4;        // 0..3
  const int bid = blockIdx.x;
  const int b   = bid >> 4;
  const int chunk0 = (bid & 15) * CHUNK;

  // O^T init (heads 8..15 zero-padded)
  for (int idx = tid; idx < 16 * 256; idx += 512){
    int h = idx >> 8, k = idx & 255;
    float v = (h < 8) ? ok[k * 8 + h] : 0.0f;
    *(unsigned short*)(sOT + h * 528 + k * 2) = f2bf(v);
  }
  sMaskB[tid] = mask[(size_t)b * S_LEN + chunk0 + tid] ? 0.0f : 1e12f;

  // persistent K^T fragments: wave w owns hidden cols [32w, 32w+32)
  short8 aF[2][8];
  #pragma unroll
  for (int mi = 0; mi < 2; ++mi){
    int hidA = l15 + ((2*w + mi) << 4);
    #pragma unroll
    for (int k = 0; k < 8; ++k){
      int col = (k << 5) + (lhi << 3);
      aF[mi][k] = *(const short8*)((const unsigned char*)KT + (((size_t)hidA << 8) + col) * 2);
    }
  }

  const unsigned char* xb = (const unsigned char*)(x + ((size_t)b * S_LEN + chunk0) * DIM);
  const int dblk = l >> 2;

  // ---- prologue: tile 0 -> regs -> stage sXB + sXT2[0]; then load tile 1
  f32x4 xr[8];
  #pragma unroll
  for (int q = 0; q < 8; ++q)
    xr[q] = *(const f32x4*)(xb + (((size_t)(8*w + q)) * DIM + 4*l) * 4);

  unsigned vd[8][2];
  #pragma unroll
  for (int q = 0; q < 8; ++q){
    vd[q][0] = pk2bf(xr[q][0], xr[q][1]);
    vd[q][1] = pk2bf(xr[q][2], xr[q][3]);
  }
  #pragma unroll
  for (int q = 0; q < 8; ++q){
    int r = 8*w + q;
    int srow = r ^ (dblk & 3);
    int off = ((l & 3) * 8) ^ (((srow >> 2) & 1) << 4);
    *(uint2*)(sXB + dblk * 2048 + srow * 32 + off) = make_uint2(vd[q][0], vd[q][1]);
  }
  #pragma unroll
  for (int i = 0; i < 4; ++i){
    int hh = i >> 1;
    unsigned dwv[4];
    #pragma unroll
    for (int j = 0; j < 4; ++j){
      unsigned a = vd[2*j][hh], c = vd[2*j+1][hh];
      dwv[j] = (i & 1) ? ((a >> 16) | (c & 0xFFFF0000u)) : ((a & 0xFFFFu) | (c << 16));
    }
    int d = 4*l + i;
    int key = ((d & 3) << 1) ^ ((d >> 2) & 7);
    *(u32x4*)(sXT2 + d * 128 + ((16*w) ^ (key << 4))) = (u32x4){dwv[0],dwv[1],dwv[2],dwv[3]};
  }
  #pragma unroll
  for (int q = 0; q < 8; ++q)
    xr[q] = *(const f32x4*)(xb + (((size_t)(TB + 8*w + q)) * DIM + 4*l) * 4);

  f32x4 acc3[2];
  acc3[0] = (f32x4){0.f,0.f,0.f,0.f};
  acc3[1] = acc3[0];
  float Lrun = 0.0f;

  __syncthreads();

  for (int it = 0; it < NIT; ++it){
    const int cur = it & 1;

    // ======== Phase A: stage sXT2[next] (tile it+1) + GEMM1 + tanh -> sT2 ========
    if (it + 1 < NIT){
      #pragma unroll
      for (int q = 0; q < 8; ++q){
        vd[q][0] = pk2bf(xr[q][0], xr[q][1]);
        vd[q][1] = pk2bf(xr[q][2], xr[q][3]);
      }
      unsigned char* dst = sXT2 + (cur ^ 1) * 32768;
      #pragma unroll
      for (int i = 0; i < 4; ++i){
        int hh = i >> 1;
        unsigned dwv[4];
        #pragma unroll
        for (int j = 0; j < 4; ++j){
          unsigned a = vd[2*j][hh], c = vd[2*j+1][hh];
          dwv[j] = (i & 1) ? ((a >> 16) | (c & 0xFFFF0000u)) : ((a & 0xFFFFu) | (c << 16));
        }
        int d = 4*l + i;
        int key = ((d & 3) << 1) ^ ((d >> 2) & 7);
        *(u32x4*)(dst + d * 128 + ((16*w) ^ (key << 4))) = (u32x4){dwv[0],dwv[1],dwv[2],dwv[3]};
      }
    }
    #pragma unroll
    for (int nt = 0; nt < 4; ++nt){
      int row = l15 + (nt << 4);
      f32x4 a0 = (f32x4){0.f,0.f,0.f,0.f};
      f32x4 a1 = a0;
      __builtin_amdgcn_s_setprio(1);
      #pragma unroll
      for (int k8 = 0; k8 < 8; ++k8){
        int dblkR = k8 * 2 + (lhi >> 1);
        int srowB = row ^ (dblkR & 3);
        int off = ((lhi & 1) * 16) ^ (((srowB >> 2) & 1) << 4);
        short8 bF = *(const short8*)(sXB + dblkR * 2048 + srowB * 32 + off);
        a0 = mfma_bf16(aF[0][k8], bF, a0);
        a1 = mfma_bf16(aF[1][k8], bF, a1);
      }
      __builtin_amdgcn_s_setprio(0);
      #pragma unroll
      for (int mi = 0; mi < 2; ++mi){
        f32x4 av = mi ? a1 : a0;
        u16x4 tv;
        #pragma unroll
        for (int r = 0; r < 4; ++r) tv[r] = f2bf(fast_tanh(av[r]));
        int hidb2 = ((((2*w + mi) << 4) + (lhi << 2))) * 2;
        *(u16x4*)(sT2 + row * 512 + (hidb2 ^ ((row & 7) << 4))) = tv;
      }
    }
    softbar();

    // ======== Phase B: stage sXB (tile it+1) + GEMM2+exp (waves 0-3) + prefetch t+2 ========
    if (it + 1 < NIT){
      #pragma unroll
      for (int q = 0; q < 8; ++q){
        int r = 8*w + q;
        int srow = r ^ (dblk & 3);
        int off = ((l & 3) * 8) ^ (((srow >> 2) & 1) << 4);
        *(uint2*)(sXB + dblk * 2048 + srow * 32 + off) = make_uint2(vd[q][0], vd[q][1]);
      }
    }
    if (w < 4){
      int row = l15 + (w << 4);
      f32x4 a2 = (f32x4){0.f,0.f,0.f,0.f};
      __builtin_amdgcn_s_setprio(1);
      #pragma unroll
      for (int k = 0; k < 8; ++k){
        int col2 = (k << 6) + (lhi << 4);
        short8 aT = *(const short8*)(sT2 + row * 512 + (col2 ^ ((row & 7) << 4)));
        short8 bO = *(const short8*)(sOT + l15 * 528 + col2);
        a2 = mfma_bf16(aT, bO, a2);
      }
      __builtin_amdgcn_s_setprio(0);
      int rbase = (w << 4) + (lhi << 2);
      float psum = 0.0f;
      #pragma unroll
      for (int r = 0; r < 4; ++r){
        // no-max softmax: |sc| <= ||O_col||_1 ~ 13 << 88 -> exp cannot overflow;
        // masked rows: exp(sc - 1e12) == 0
        float p = __expf(a2[r] - sMaskB[it * TB + rbase + r]);
        unsigned short pb = f2bf(p);
        psum += bf2f(pb);
        *(unsigned short*)(sPT + l15 * 144 + (rbase + r) * 2) = pb;
      }
      psum += __shfl_xor(psum, 16);
      psum += __shfl_xor(psum, 32);
      Lrun += psum;                 // every lane: head l15 total over this wave's 16 rows
    }
    if (it + 2 < NIT){
      #pragma unroll
      for (int q = 0; q < 8; ++q)
        xr[q] = *(const f32x4*)(xb + (((size_t)((it+2)*TB + 8*w + q)) * DIM + 4*l) * 4);
    }
    softbar();

    // ======== Phase C: GEMM3: pooled[head][d] += P^T · X  (reads sXT2[cur], sPT) ========
    {
      short8 aP0 = *(const short8*)(sPT + l15 * 144 + lhi * 16);        // r 0..31
      short8 aP1 = *(const short8*)(sPT + l15 * 144 + 64 + lhi * 16);   // r 32..63
      const unsigned char* srcX = sXT2 + cur * 32768;
      __builtin_amdgcn_s_setprio(1);
      #pragma unroll
      for (int mi = 0; mi < 2; ++mi){
        int d = (2*w + mi) * 16 + l15;
        int key = ((d & 3) << 1) ^ ((d >> 2) & 7);
        const unsigned char* pd = srcX + d * 128;
        short8 b0 = *(const short8*)(pd + (((     lhi * 16)) ^ (key << 4)));
        short8 b1 = *(const short8*)(pd + (((64 + lhi * 16)) ^ (key << 4)));
        acc3[mi] = mfma_bf16(aP0, b0, acc3[mi]);
        acc3[mi] = mfma_bf16(aP1, b1, acc3[mi]);
      }
      __builtin_amdgcn_s_setprio(0);
    }
    softbar();
  }

  // epilogue: per-chunk partials.  acc3[mi]: head = lhi*4+reg, d = (2w+mi)*16 + l15
  if (lhi < 2){      // only heads 0..7 are real
    #pragma unroll
    for (int mi = 0; mi < 2; ++mi){
      int d = ((2*w + mi) << 4) + l15;
      #pragma unroll
      for (int r = 0; r < 4; ++r){
        int h = (lhi << 2) + r;
        ACC[((size_t)bid * 8 + h) * 256 + d] = acc3[mi][r];
      }
    }
  }
  if (w < 4 && l < 16) sWSum[w][l] = Lrun;
  __syncthreads();
  if (tid < 8)
    ML[bid * 8 + tid] = sWSum[0][tid] + sWSum[1][tid] + sWSum[2][tid] + sWSum[3][tid];
}

// ---- merge 16 chunk-partials per (batch, head): no max needed (fixed shift = 0)
__global__ void k_merge(const float* __restrict__ ACC, const float* __restrict__ ML,
                        float* __restrict__ out){
  int b = blockIdx.x >> 3;
  int h = blockIdx.x & 7;
  int d = threadIdx.x;                      // 256
  float L = 0.0f, V = 0.0f;
  #pragma unroll 4
  for (int c = 0; c < 16; ++c){
    int blk = b * 16 + c;
    L += ML[blk * 8 + h];
    V += ACC[((size_t)blk * 8 + h) * 256 + d];
  }
  out[(size_t)b * 2048 + h * 256 + d] = V / L;
}

extern "C" void kernel_launch(void* const* d_in, const int* in_sizes, int n_in,
                              void* d_out, int out_size, void* d_ws, size_t ws_size,
                              hipStream_t stream){
  const float* x   = (const float*)d_in[0];
  const int*  mask = (const int*) d_in[1];
  const float* kk  = (const float*)d_in[2];
  const float* ok  = (const float*)d_in[3];
  float* out = (float*)d_out;

  // ws layout: KT bf16 (128 KiB) | ACC f32 256*8*256 (2 MiB) | ML f32 256*8 (8 KiB)
  unsigned short* KT = (unsigned short*)d_ws;
  float* ACC = (float*)((char*)d_ws + 131072);
  float* ML  = (float*)((char*)d_ws + 131072 + 2097152);

  k_prep <<<128, 512, 0, stream>>>(kk, KT);
  k_main <<<NBLK, 512, 0, stream>>>(x, mask, ok, KT, ACC, ML);
  k_merge<<<128, 256, 0, stream>>>(ACC, ML, out);
}

// Round 13
// 56.961 us; speedup vs baseline: 1.3661x; 1.0222x over previous
//
#include <hip/hip_runtime.h>

#define S_LEN 8192
#define DIM   256
#define CHUNK 512
#define TB    64
#define NIT   8
#define NBLK  256

typedef __attribute__((ext_vector_type(8))) short          short8;
typedef __attribute__((ext_vector_type(4))) unsigned short u16x4;
typedef __attribute__((ext_vector_type(4))) unsigned int   u32x4;
typedef __attribute__((ext_vector_type(4))) float          f32x4;
typedef __attribute__((ext_vector_type(8))) __bf16         bf16x8;

// native cast -> v_cvt RNE
static __device__ __forceinline__ unsigned short f2bf(float f){
  return __builtin_bit_cast(unsigned short, (__bf16)f);
}
static __device__ __forceinline__ unsigned pk2bf(float lo, float hi){
  return (unsigned)f2bf(lo) | ((unsigned)f2bf(hi) << 16);
}
static __device__ __forceinline__ float bf2f(unsigned short h){
  unsigned int u = ((unsigned int)h) << 16;
  return __builtin_bit_cast(float, u);
}
static __device__ __forceinline__ float fast_tanh(float x){
  float e = __expf(2.0f * x);
  return 1.0f - 2.0f / (e + 1.0f);
}
static __device__ __forceinline__ f32x4 mfma_bf16(short8 a, short8 b, f32x4 c){
  return __builtin_amdgcn_mfma_f32_16x16x32_bf16(
      __builtin_bit_cast(bf16x8, a), __builtin_bit_cast(bf16x8, b), c, 0, 0, 0);
}
// barrier draining LDS ops only (no vmcnt drain)
static __device__ __forceinline__ void softbar(){
  asm volatile("s_waitcnt lgkmcnt(0)\n\ts_barrier" ::: "memory");
}

// ---- prep: KT[n][k] = bf16(k_kernel[k][n])
__global__ void k_prep(const float* __restrict__ kk, unsigned short* __restrict__ KT){
  int idx = blockIdx.x * 512 + threadIdx.x;     // 128 x 512 = 65536
  int n = idx >> 8, k = idx & 255;
  KT[(n << 8) + k] = f2bf(kk[(k << 8) + n]);
}

// sXB : (r,d) at dblk*2048 + srow*32 + off; dblk=d>>4, srow=r^(dblk&3),
//       off=((d&15)*2)^(((srow>>2)&1)<<4)        (d-contig, GEMM1-B)  [R5-verified]
// sXT2: (r,d) at buf*32768 + d*128 + ((r*2)^(key(d)<<4)), key=((d&3)<<1)^((d>>2)&7)
//       (r-contig, GEMM3-B)  [R5-verified, double-buffered]
// Schedule (2 barriers/iter):
//   A(t): GEMM3(t-1) [sXT2[(t-1)&1], sPT[(t-1)&1]]  ||  GEMM1(t) [sXB] -> sT2
//   B(t): GEMM2(t) [sT2] -> sPT[t&1] (waves 0-3)  ||  stage tile t+1 -> sXB + sXT2[(t+1)&1]
//         || prefetch xr <- tile t+2

__global__ __launch_bounds__(512, 2) void k_main(
    const float* __restrict__ x, const int* __restrict__ mask,
    const float* __restrict__ ok, const unsigned short* __restrict__ KT,
    float* __restrict__ ACC, float* __restrict__ ML)
{
  __shared__ __align__(16) unsigned char sXB [32768];
  __shared__ __align__(16) unsigned char sXT2[65536];   // 2 buffers
  __shared__ __align__(16) unsigned char sT2 [32768];   // tanh(h) [64][256] bf16, swz ((row&7)<<4)
  __shared__ __align__(16) unsigned char sOT [16*528];  // O^T [16][256] bf16 (+pad), rows 8..15 zero
  __shared__ __align__(16) unsigned char sPT [2*2304];  // P^T [16][64] bf16 (+pad), 2 buffers
  __shared__ float sWSum[4][16];
  __shared__ float sMaskB[CHUNK];

  const int tid = threadIdx.x;
  const int w   = tid >> 6;      // wave 0..7
  const int l   = tid & 63;
  const int l15 = l & 15;
  const int lhi = l >> 4;        // 0..3
  const int bid = blockIdx.x;
  const int b   = bid >> 4;
  const int chunk0 = (bid & 15) * CHUNK;

  // O^T init (heads 8..15 zero-padded)
  for (int idx = tid; idx < 16 * 256; idx += 512){
    int h = idx >> 8, k = idx & 255;
    float v = (h < 8) ? ok[k * 8 + h] : 0.0f;
    *(unsigned short*)(sOT + h * 528 + k * 2) = f2bf(v);
  }
  sMaskB[tid] = mask[(size_t)b * S_LEN + chunk0 + tid] ? 0.0f : 1e12f;

  // persistent K^T fragments: wave w owns hidden cols [32w, 32w+32)
  short8 aF[2][8];
  #pragma unroll
  for (int mi = 0; mi < 2; ++mi){
    int hidA = l15 + ((2*w + mi) << 4);
    #pragma unroll
    for (int k = 0; k < 8; ++k){
      int col = (k << 5) + (lhi << 3);
      aF[mi][k] = *(const short8*)((const unsigned char*)KT + (((size_t)hidA << 8) + col) * 2);
    }
  }

  const unsigned char* xb = (const unsigned char*)(x + ((size_t)b * S_LEN + chunk0) * DIM);
  const int dblk = l >> 2;

  // ---- prologue: tile 0 -> regs -> stage sXB + sXT2[0]; then load xr <- tile 1
  f32x4 xr[8];
  #pragma unroll
  for (int q = 0; q < 8; ++q)
    xr[q] = *(const f32x4*)(xb + (((size_t)(8*w + q)) * DIM + 4*l) * 4);

  {
    unsigned vd[8][2];
    #pragma unroll
    for (int q = 0; q < 8; ++q){
      vd[q][0] = pk2bf(xr[q][0], xr[q][1]);
      vd[q][1] = pk2bf(xr[q][2], xr[q][3]);
    }
    #pragma unroll
    for (int q = 0; q < 8; ++q){
      int r = 8*w + q;
      int srow = r ^ (dblk & 3);
      int off = ((l & 3) * 8) ^ (((srow >> 2) & 1) << 4);
      *(uint2*)(sXB + dblk * 2048 + srow * 32 + off) = make_uint2(vd[q][0], vd[q][1]);
    }
    #pragma unroll
    for (int i = 0; i < 4; ++i){
      int hh = i >> 1;
      unsigned dwv[4];
      #pragma unroll
      for (int j = 0; j < 4; ++j){
        unsigned a = vd[2*j][hh], c = vd[2*j+1][hh];
        dwv[j] = (i & 1) ? ((a >> 16) | (c & 0xFFFF0000u)) : ((a & 0xFFFFu) | (c << 16));
      }
      int d = 4*l + i;
      int key = ((d & 3) << 1) ^ ((d >> 2) & 7);
      *(u32x4*)(sXT2 + d * 128 + ((16*w) ^ (key << 4))) = (u32x4){dwv[0],dwv[1],dwv[2],dwv[3]};
    }
  }
  #pragma unroll
  for (int q = 0; q < 8; ++q)
    xr[q] = *(const f32x4*)(xb + (((size_t)(TB + 8*w + q)) * DIM + 4*l) * 4);

  f32x4 acc3[2];
  acc3[0] = (f32x4){0.f,0.f,0.f,0.f};
  acc3[1] = acc3[0];
  float Lrun = 0.0f;

  __syncthreads();

  for (int it = 0; it < NIT; ++it){
    // ======== Phase A: GEMM3(it-1) || GEMM1(it) + tanh -> sT2 ========
    if (it > 0){
      const int pb = (it - 1) & 1;
      short8 aP0 = *(const short8*)(sPT + pb * 2304 + l15 * 144 + lhi * 16);       // r 0..31
      short8 aP1 = *(const short8*)(sPT + pb * 2304 + l15 * 144 + 64 + lhi * 16);  // r 32..63
      const unsigned char* srcX = sXT2 + pb * 32768;
      #pragma unroll
      for (int mi = 0; mi < 2; ++mi){
        int d = (2*w + mi) * 16 + l15;
        int key = ((d & 3) << 1) ^ ((d >> 2) & 7);
        const unsigned char* pd = srcX + d * 128;
        short8 b0 = *(const short8*)(pd + (((     lhi * 16)) ^ (key << 4)));
        short8 b1 = *(const short8*)(pd + (((64 + lhi * 16)) ^ (key << 4)));
        acc3[mi] = mfma_bf16(aP0, b0, acc3[mi]);
        acc3[mi] = mfma_bf16(aP1, b1, acc3[mi]);
      }
    }
    #pragma unroll
    for (int nt = 0; nt < 4; ++nt){
      int row = l15 + (nt << 4);
      f32x4 a0 = (f32x4){0.f,0.f,0.f,0.f};
      f32x4 a1 = a0;
      __builtin_amdgcn_s_setprio(1);
      #pragma unroll
      for (int k8 = 0; k8 < 8; ++k8){
        int dblkR = k8 * 2 + (lhi >> 1);
        int srowB = row ^ (dblkR & 3);
        int off = ((lhi & 1) * 16) ^ (((srowB >> 2) & 1) << 4);
        short8 bF = *(const short8*)(sXB + dblkR * 2048 + srowB * 32 + off);
        a0 = mfma_bf16(aF[0][k8], bF, a0);
        a1 = mfma_bf16(aF[1][k8], bF, a1);
      }
      __builtin_amdgcn_s_setprio(0);
      #pragma unroll
      for (int mi = 0; mi < 2; ++mi){
        f32x4 av = mi ? a1 : a0;
        u16x4 tv;
        #pragma unroll
        for (int r = 0; r < 4; ++r) tv[r] = f2bf(fast_tanh(av[r]));
        int hidb2 = ((((2*w + mi) << 4) + (lhi << 2))) * 2;
        *(u16x4*)(sT2 + row * 512 + (hidb2 ^ ((row & 7) << 4))) = tv;
      }
    }
    softbar();

    // ======== Phase B: GEMM2(it)+exp (waves 0-3) || stage tile it+1 || prefetch it+2 ========
    if (it + 1 < NIT){
      unsigned vd[8][2];
      #pragma unroll
      for (int q = 0; q < 8; ++q){
        vd[q][0] = pk2bf(xr[q][0], xr[q][1]);
        vd[q][1] = pk2bf(xr[q][2], xr[q][3]);
      }
      #pragma unroll
      for (int q = 0; q < 8; ++q){
        int r = 8*w + q;
        int srow = r ^ (dblk & 3);
        int off = ((l & 3) * 8) ^ (((srow >> 2) & 1) << 4);
        *(uint2*)(sXB + dblk * 2048 + srow * 32 + off) = make_uint2(vd[q][0], vd[q][1]);
      }
      unsigned char* dst = sXT2 + ((it + 1) & 1) * 32768;
      #pragma unroll
      for (int i = 0; i < 4; ++i){
        int hh = i >> 1;
        unsigned dwv[4];
        #pragma unroll
        for (int j = 0; j < 4; ++j){
          unsigned a = vd[2*j][hh], c = vd[2*j+1][hh];
          dwv[j] = (i & 1) ? ((a >> 16) | (c & 0xFFFF0000u)) : ((a & 0xFFFFu) | (c << 16));
        }
        int d = 4*l + i;
        int key = ((d & 3) << 1) ^ ((d >> 2) & 7);
        *(u32x4*)(dst + d * 128 + ((16*w) ^ (key << 4))) = (u32x4){dwv[0],dwv[1],dwv[2],dwv[3]};
      }
    }
    if (w < 4){
      int row = l15 + (w << 4);
      f32x4 a2 = (f32x4){0.f,0.f,0.f,0.f};
      __builtin_amdgcn_s_setprio(1);
      #pragma unroll
      for (int k = 0; k < 8; ++k){
        int col2 = (k << 6) + (lhi << 4);
        short8 aT = *(const short8*)(sT2 + row * 512 + (col2 ^ ((row & 7) << 4)));
        short8 bO = *(const short8*)(sOT + l15 * 528 + col2);
        a2 = mfma_bf16(aT, bO, a2);
      }
      __builtin_amdgcn_s_setprio(0);
      int rbase = (w << 4) + (lhi << 2);
      float psum = 0.0f;
      #pragma unroll
      for (int r = 0; r < 4; ++r){
        // no-max softmax: |sc| <= ||O_col||_1 ~ 13 << 88 -> exp cannot overflow;
        // masked rows: exp(sc - 1e12) == 0
        float p = __expf(a2[r] - sMaskB[it * TB + rbase + r]);
        unsigned short pb2 = f2bf(p);
        psum += bf2f(pb2);
        *(unsigned short*)(sPT + (it & 1) * 2304 + l15 * 144 + (rbase + r) * 2) = pb2;
      }
      psum += __shfl_xor(psum, 16);
      psum += __shfl_xor(psum, 32);
      Lrun += psum;                 // every lane: head l15 total over this wave's 16 rows
    }
    if (it + 2 < NIT){
      #pragma unroll
      for (int q = 0; q < 8; ++q)
        xr[q] = *(const f32x4*)(xb + (((size_t)((it+2)*TB + 8*w + q)) * DIM + 4*l) * 4);
    }
    softbar();
  }

  // ---- epilogue GEMM3 for the last tile ----
  {
    const int pb = (NIT - 1) & 1;
    short8 aP0 = *(const short8*)(sPT + pb * 2304 + l15 * 144 + lhi * 16);
    short8 aP1 = *(const short8*)(sPT + pb * 2304 + l15 * 144 + 64 + lhi * 16);
    const unsigned char* srcX = sXT2 + pb * 32768;
    #pragma unroll
    for (int mi = 0; mi < 2; ++mi){
      int d = (2*w + mi) * 16 + l15;
      int key = ((d & 3) << 1) ^ ((d >> 2) & 7);
      const unsigned char* pd = srcX + d * 128;
      short8 b0 = *(const short8*)(pd + (((     lhi * 16)) ^ (key << 4)));
      short8 b1 = *(const short8*)(pd + (((64 + lhi * 16)) ^ (key << 4)));
      acc3[mi] = mfma_bf16(aP0, b0, acc3[mi]);
      acc3[mi] = mfma_bf16(aP1, b1, acc3[mi]);
    }
  }

  // epilogue: per-chunk partials.  acc3[mi]: head = lhi*4+reg, d = (2w+mi)*16 + l15
  if (lhi < 2){      // only heads 0..7 are real
    #pragma unroll
    for (int mi = 0; mi < 2; ++mi){
      int d = ((2*w + mi) << 4) + l15;
      #pragma unroll
      for (int r = 0; r < 4; ++r){
        int h = (lhi << 2) + r;
        ACC[((size_t)bid * 8 + h) * 256 + d] = acc3[mi][r];
      }
    }
  }
  if (w < 4 && l < 16) sWSum[w][l] = Lrun;
  __syncthreads();
  if (tid < 8)
    ML[bid * 8 + tid] = sWSum[0][tid] + sWSum[1][tid] + sWSum[2][tid] + sWSum[3][tid];
}

// ---- merge 16 chunk-partials per (batch, head): no max needed (fixed shift = 0)
__global__ void k_merge(const float* __restrict__ ACC, const float* __restrict__ ML,
                        float* __restrict__ out){
  int b = blockIdx.x >> 3;
  int h = blockIdx.x & 7;
  int d = threadIdx.x;                      // 256
  float L = 0.0f, V = 0.0f;
  #pragma unroll 4
  for (int c = 0; c < 16; ++c){
    int blk = b * 16 + c;
    L += ML[blk * 8 + h];
    V += ACC[((size_t)blk * 8 + h) * 256 + d];
  }
  out[(size_t)b * 2048 + h * 256 + d] = V / L;
}

extern "C" void kernel_launch(void* const* d_in, const int* in_sizes, int n_in,
                              void* d_out, int out_size, void* d_ws, size_t ws_size,
                              hipStream_t stream){
  const float* x   = (const float*)d_in[0];
  const int*  mask = (const int*) d_in[1];
  const float* kk  = (const float*)d_in[2];
  const float* ok  = (const float*)d_in[3];
  float* out = (float*)d_out;

  // ws layout: KT bf16 (128 KiB) | ACC f32 256*8*256 (2 MiB) | ML f32 256*8 (8 KiB)
  unsigned short* KT = (unsigned short*)d_ws;
  float* ACC = (float*)((char*)d_ws + 131072);
  float* ML  = (float*)((char*)d_ws + 131072 + 2097152);

  k_prep <<<128, 512, 0, stream>>>(kk, KT);
  k_main <<<NBLK, 512, 0, stream>>>(x, mask, ok, KT, ACC, ML);
  k_merge<<<128, 256, 0, stream>>>(ACC, ML, out);
}